// Round 1
// baseline (3442.284 us; speedup 1.0000x reference)
//
#include <hip/hip_runtime.h>

#define B_ 4
#define R_ 36
#define C_ 3
#define H_ 384
#define W_ 224
#define KS 64
#define OY 321   // conv-out rows actually needed (full rows 32..352)
#define OX 161   // conv-out cols actually needed (full cols 32..192)
#define HC 320
#define WC 160
#define WSTRIDE (C_*KS*KS)   // 12288 floats between consecutive r in kernel tensor
#define BLKS_PER_BATCH 7200  // (36*320*160)/256

__device__ __forceinline__ float wave_max(float v) {
    #pragma unroll
    for (int off = 32; off > 0; off >>= 1) v = fmaxf(v, __shfl_down(v, off, 64));
    return v;
}
__device__ __forceinline__ float wave_sum(float v) {
    #pragma unroll
    for (int off = 32; off > 0; off >>= 1) v += __shfl_down(v, off, 64);
    return v;
}

// Direct fp32 conv on the needed 321x161 window; no padding logic needed.
// Grid: (3 x-blocks of 64, 321 y rows, 4 batches). Block: 256 = 4 waves.
// Wave rg handles r = rg*9 .. rg*9+8 (9 accumulators). Lane = x offset.
// Weights are wave-uniform -> scalar loads (s_load_dwordx4).
__global__ __launch_bounds__(256) void conv_kernel(
    const float* __restrict__ in, const float* __restrict__ wk, float* __restrict__ out)
{
    const int xb = blockIdx.x;
    const int y0 = blockIdx.y;
    const int b  = blockIdx.z;
    const int t  = threadIdx.x;
    const int xo = t & 63;
    const int rg = __builtin_amdgcn_readfirstlane(t >> 6);   // wave-uniform r-group
    const int x0b = xb * 64;
    const int x0 = x0b + xo;

    __shared__ float L[KS][128];   // input rows y0..y0+63, cols x0b..x0b+127 (one channel)

    float acc[9];
    #pragma unroll
    for (int i = 0; i < 9; i++) acc[i] = 0.f;

    for (int c = 0; c < C_; c++) {
        __syncthreads();   // protect previous channel's reads
        const float* src = in + (size_t)(b*C_ + c)*H_*W_;
        #pragma unroll
        for (int k = 0; k < 8; k++) {
            int idx = t + 256*k;       // 0..2047 = 64 rows x 32 float4
            int row = idx >> 5;
            int c4  = (idx & 31) * 4;
            int gx  = x0b + c4;
            float4 v = make_float4(0.f, 0.f, 0.f, 0.f);
            if (gx <= W_ - 4) v = *(const float4*)(src + (size_t)(y0 + row)*W_ + gx);
            *(float4*)&L[row][c4] = v;
        }
        __syncthreads();

        const float* wbase = wk + (size_t)((b*R_ + rg*9)*C_ + c)*KS*KS;
        for (int ky = 0; ky < KS; ky++) {
            const float* Lr = &L[ky][xo];
            const float* wrow = wbase + ky*KS;
            #pragma unroll 2
            for (int g = 0; g < 16; g++) {
                float s0 = Lr[g*4+0];
                float s1 = Lr[g*4+1];
                float s2 = Lr[g*4+2];
                float s3 = Lr[g*4+3];
                #pragma unroll
                for (int i = 0; i < 9; i++) {
                    const float* wp = wrow + i*WSTRIDE + g*4;
                    acc[i] = fmaf(s0, wp[0], acc[i]);
                    acc[i] = fmaf(s1, wp[1], acc[i]);
                    acc[i] = fmaf(s2, wp[2], acc[i]);
                    acc[i] = fmaf(s3, wp[3], acc[i]);
                }
            }
        }
    }

    if (x0 < OX) {
        #pragma unroll
        for (int i = 0; i < 9; i++) {
            out[((size_t)(b*R_ + rg*9 + i)*OY + y0)*OX + x0] = acc[i];
        }
    }
}

// Bilinear resize (matches jax.image.resize bilinear, antialias=False) + crop,
// expressed directly in the cropped/needed coordinate frame. Also emits
// per-block max partials for the softmax.
__global__ __launch_bounds__(256) void resize_kernel(
    const float* __restrict__ cv, float* __restrict__ out, float* __restrict__ pmax)
{
    const int t = threadIdx.x;
    const int idx = blockIdx.x * 256 + t;
    const int j = idx % WC;
    const int rest = idx / WC;
    const int i = rest % HC;
    const int br = rest / HC;    // b*36+r

    float ry = (i + 32.5f) * (385.0f/384.0f) - 32.5f;   // in [0.084, 319.916]
    int   iy = (int)ry;
    float fy = ry - (float)iy;
    float rx = (j + 32.5f) * (225.0f/224.0f) - 32.5f;   // in [0.145, 159.856]
    int   ix = (int)rx;
    float fx = rx - (float)ix;

    const float* p = cv + ((size_t)br*OY + iy)*OX + ix;
    float v00 = p[0], v01 = p[1], v10 = p[OX], v11 = p[OX+1];
    float v = (1.f-fy)*((1.f-fx)*v00 + fx*v01) + fy*((1.f-fx)*v10 + fx*v11);
    out[idx] = v;

    __shared__ float sm[4];
    float m = wave_max(v);
    if ((t & 63) == 0) sm[t >> 6] = m;
    __syncthreads();
    if (t == 0) pmax[blockIdx.x] = fmaxf(fmaxf(sm[0], sm[1]), fmaxf(sm[2], sm[3]));
}

__global__ __launch_bounds__(256) void reduce_kernel(
    const float* __restrict__ part, float* __restrict__ res, int n, int is_sum)
{
    const int b = blockIdx.x;
    const int t = threadIdx.x;
    const float* p = part + (size_t)b*n;
    float v = is_sum ? 0.f : -3.0e38f;
    for (int k = t; k < n; k += 256) v = is_sum ? (v + p[k]) : fmaxf(v, p[k]);
    __shared__ float sm[4];
    float w = is_sum ? wave_sum(v) : wave_max(v);
    if ((t & 63) == 0) sm[t >> 6] = w;
    __syncthreads();
    if (t == 0) {
        float r = is_sum ? (sm[0]+sm[1]+sm[2]+sm[3])
                         : fmaxf(fmaxf(sm[0], sm[1]), fmaxf(sm[2], sm[3]));
        res[b] = r;
    }
}

__global__ __launch_bounds__(256) void exp_kernel(
    float* __restrict__ out, const float* __restrict__ bmax, float* __restrict__ psum)
{
    const int t = threadIdx.x;
    const int idx = blockIdx.x * 256 + t;
    const int b = blockIdx.x / BLKS_PER_BATCH;
    float e = expf(out[idx] - bmax[b]);
    out[idx] = e;
    __shared__ float sm[4];
    float s = wave_sum(e);
    if ((t & 63) == 0) sm[t >> 6] = s;
    __syncthreads();
    if (t == 0) psum[blockIdx.x] = sm[0]+sm[1]+sm[2]+sm[3];
}

__global__ __launch_bounds__(256) void scale_kernel(
    float* __restrict__ out, const float* __restrict__ bsum)
{
    const int idx = blockIdx.x * 256 + threadIdx.x;
    const int b = blockIdx.x / BLKS_PER_BATCH;
    out[idx] = out[idx] / bsum[b];
}

extern "C" void kernel_launch(void* const* d_in, const int* in_sizes, int n_in,
                              void* d_out, int out_size, void* d_ws, size_t ws_size,
                              hipStream_t stream)
{
    const float* logits = (const float*)d_in[0];   // (4,3,384,224) fp32
    const float* wk     = (const float*)d_in[1];   // (144,3,64,64) fp32
    float* out = (float*)d_out;                    // (4,36,320,160) fp32
    float* wsF = (float*)d_ws;

    float* convOut = wsF;                 // 144*321*161 = 7,442,064 floats
    float* pmax    = wsF + 7500000;       // 28800 floats
    float* psum    = pmax + 28800;        // 28800 floats
    float* bmax    = psum + 28800;        // 4 floats (pad 8)
    float* bsum    = bmax + 8;            // 4 floats

    dim3 gc(3, OY, B_);
    hipLaunchKernelGGL(conv_kernel,   gc,          dim3(256), 0, stream, logits, wk, convOut);
    hipLaunchKernelGGL(resize_kernel, dim3(28800), dim3(256), 0, stream, convOut, out, pmax);
    hipLaunchKernelGGL(reduce_kernel, dim3(4),     dim3(256), 0, stream, pmax, bmax, BLKS_PER_BATCH, 0);
    hipLaunchKernelGGL(exp_kernel,    dim3(28800), dim3(256), 0, stream, out, bmax, psum);
    hipLaunchKernelGGL(reduce_kernel, dim3(4),     dim3(256), 0, stream, psum, bsum, BLKS_PER_BATCH, 1);
    hipLaunchKernelGGL(scale_kernel,  dim3(28800), dim3(256), 0, stream, out, bsum);
}

// Round 2
// 874.685 us; speedup vs baseline: 3.9355x; 3.9355x over previous
//
#include <hip/hip_runtime.h>

typedef short bf16x8 __attribute__((ext_vector_type(8)));
typedef float f32x4  __attribute__((ext_vector_type(4)));
typedef unsigned short u16;

#define B_ 4
#define R_ 36
#define RP 48          // r padded to 3 m-tiles of 16
#define C_ 3
#define H_ 384
#define W_ 224
#define KS 64
#define OY 321         // conv-out rows needed (full rows 32..352)
#define OX 161         // conv-out cols needed (full cols 32..192)
#define HC 320
#define WC 160
#define NX 96          // x extent per WG
#define NT 6           // n-tiles (16 x each)
#define MT 3           // m-tiles (16 r each)
#define LCOLS 160      // NX-1 + 63 = 158 -> 160 cols staged
#define PITCH 72       // row pitch: mult of 8 (16B frag align), 144B = 16*9 -> 2-way banks only
#define BLKS_PER_BATCH 7200

__device__ __forceinline__ u16 bf16rtn(float v) {
    union { float f; unsigned u; } U; U.f = v;
    unsigned r = U.u + 0x7fffu + ((U.u >> 16) & 1u);
    return (u16)(r >> 16);
}
__device__ __forceinline__ float bf16tof(u16 h) {
    union { float f; unsigned u; } U; U.u = ((unsigned)h) << 16; return U.f;
}

__device__ __forceinline__ float wave_max(float v) {
    #pragma unroll
    for (int off = 32; off > 0; off >>= 1) v = fmaxf(v, __shfl_down(v, off, 64));
    return v;
}
__device__ __forceinline__ float wave_sum(float v) {
    #pragma unroll
    for (int off = 32; off > 0; off >>= 1) v += __shfl_down(v, off, 64);
    return v;
}

// Split fp32 weights into bf16 hi/lo planes, transposed to [b][r48][c][kx][ky], r>=36 zeroed.
__global__ __launch_bounds__(256) void prep_weights(
    const float* __restrict__ wk, u16* __restrict__ wh, u16* __restrict__ wl)
{
    int d = blockIdx.x * 256 + threadIdx.x;           // [0, 4*48*3*64*64)
    int ky = d & 63;
    int kx = (d >> 6) & 63;
    int rc = d >> 12;                                  // (b*48+r)*3 + c
    int c  = rc % 3;
    int br = rc / 3;
    int r  = br % RP;
    int b  = br / RP;
    float v = 0.f;
    if (r < R_) v = wk[(((size_t)(b*R_ + r)*C_ + c)*KS + (size_t)ky)*KS + kx];
    u16 h = bf16rtn(v);
    float lo = v - bf16tof(h);
    wh[d] = h;
    wl[d] = bf16rtn(lo);
}

// Implicit-GEMM conv via MFMA 16x16x32 bf16, 3-product hi/lo split.
// Grid: (2 xb, 321 y, 4 b). Block 256 = 4 waves; waves split kx (kx % 4 == wave).
// C[r][y][x] = sum_{c,kx} sum_{ky} Wt[b,r,c,kx,ky] * I[b,c,y+ky,x+kx]
//   A[m=lane&15][k=quad*8+j] = Wt[...]   (16B contiguous global load)
//   B[k=quad*8+j][n=lane&15] = Lt[col=n0+nu+kx][row=kyc+8q+j]  (ds_read_b128)
__global__ __launch_bounds__(256) void conv_mfma(
    const float* __restrict__ in, const u16* __restrict__ wth, const u16* __restrict__ wtl,
    float* __restrict__ out)
{
    __shared__ u16 smem[2 * LCOLS * PITCH];   // 46080 B; reused for the k-split reduction
    u16* Lh = smem;
    u16* Ll = smem + LCOLS * PITCH;

    const int xb  = blockIdx.x;
    const int y0  = blockIdx.y;
    const int b   = blockIdx.z;
    const int t   = threadIdx.x;
    const int w   = t >> 6;
    const int lane = t & 63;
    const int nu  = lane & 15;
    const int q   = lane >> 4;
    const int x0  = xb * NX;

    f32x4 acc[MT][NT];
    #pragma unroll
    for (int mi = 0; mi < MT; mi++)
        #pragma unroll
        for (int n = 0; n < NT; n++)
            acc[mi][n] = (f32x4){0.f, 0.f, 0.f, 0.f};

    const int rp2 = (t >> 3) * 2;   // even row 0..62
    const int fc  = t & 7;

    for (int c = 0; c < C_; c++) {
        __syncthreads();
        // ---- stage input rows y0..y0+63, cols x0..x0+159, transposed + bf16-split ----
        const float* src = in + ((size_t)(b*C_ + c))*H_*W_ + (size_t)y0*W_;
        #pragma unroll
        for (int i = 0; i < 5; i++) {
            int c4 = (fc + 8*i) * 4;
            int gx = x0 + c4;
            float4 va = make_float4(0.f,0.f,0.f,0.f), vb = va;
            if (gx < W_) {   // float4 chunks are entirely in or entirely out (224 % 4 == 0)
                va = *(const float4*)(src + (size_t)rp2*W_ + gx);
                vb = *(const float4*)(src + (size_t)(rp2+1)*W_ + gx);
            }
            const float* pa = &va.x;
            const float* pb = &vb.x;
            #pragma unroll
            for (int j = 0; j < 4; j++) {
                u16 ha = bf16rtn(pa[j]);
                u16 hb = bf16rtn(pb[j]);
                u16 la = bf16rtn(pa[j] - bf16tof(ha));
                u16 lb = bf16rtn(pb[j] - bf16tof(hb));
                *(unsigned*)&Lh[(c4+j)*PITCH + rp2] = (unsigned)ha | ((unsigned)hb << 16);
                *(unsigned*)&Ll[(c4+j)*PITCH + rp2] = (unsigned)la | ((unsigned)lb << 16);
            }
        }
        __syncthreads();

        // ---- MFMA over this channel; wave w owns kx in {w, w+4, ..., w+60} ----
        for (int kxi = 0; kxi < 16; kxi++) {
            int kx = kxi*4 + w;
            #pragma unroll
            for (int kycI = 0; kycI < 2; kycI++) {
                int kyc = kycI * 32;
                bf16x8 Ah[MT], Al[MT];
                #pragma unroll
                for (int mi = 0; mi < MT; mi++) {
                    size_t off = ((((size_t)(b*RP + mi*16 + nu)*C_ + c)*KS + kx)*KS) + kyc + 8*q;
                    Ah[mi] = *(const bf16x8*)(wth + off);
                    Al[mi] = *(const bf16x8*)(wtl + off);
                }
                #pragma unroll
                for (int n = 0; n < NT; n++) {
                    int col = n*16 + nu + kx;
                    const u16* ph = &Lh[col*PITCH + kyc + 8*q];
                    bf16x8 Bh = *(const bf16x8*)ph;
                    bf16x8 Bl = *(const bf16x8*)(ph + LCOLS*PITCH);
                    #pragma unroll
                    for (int mi = 0; mi < MT; mi++) {
                        acc[mi][n] = __builtin_amdgcn_mfma_f32_16x16x32_bf16(Ah[mi], Bh, acc[mi][n], 0, 0, 0);
                        acc[mi][n] = __builtin_amdgcn_mfma_f32_16x16x32_bf16(Ah[mi], Bl, acc[mi][n], 0, 0, 0);
                        acc[mi][n] = __builtin_amdgcn_mfma_f32_16x16x32_bf16(Al[mi], Bh, acc[mi][n], 0, 0, 0);
                    }
                }
            }
        }
    }

    // ---- k-split reduction across the 4 waves, 2 rounds of 9 fragments ----
    float* red = (float*)smem;   // [4 waves][9 frags][64 lanes][4] f32 = 36864 B
    const int lsrc = t >> 2;
    const int isrc = t & 3;
    #pragma unroll
    for (int round = 0; round < 2; round++) {
        __syncthreads();
        #pragma unroll
        for (int k = 0; k < 9; k++) {
            int f  = round*9 + k;
            int mi = f / NT, n = f % NT;
            *(f32x4*)&red[((w*9 + k)*64 + lane)*4] = acc[mi][n];
        }
        __syncthreads();
        #pragma unroll
        for (int k = 0; k < 9; k++) {
            float s = red[((0*9+k)*64 + lsrc)*4 + isrc]
                    + red[((1*9+k)*64 + lsrc)*4 + isrc]
                    + red[((2*9+k)*64 + lsrc)*4 + isrc]
                    + red[((3*9+k)*64 + lsrc)*4 + isrc];
            int f  = round*9 + k;
            int mi = f / NT, n = f % NT;
            int r  = mi*16 + (lsrc >> 4)*4 + isrc;
            int x  = x0 + n*16 + (lsrc & 15);
            if (r < R_ && x < OX)
                out[((size_t)(b*R_ + r)*OY + y0)*OX + x] = s;
        }
    }
}

// Bilinear resize (iy==i, ix==j for the needed range) + per-block max partials.
__global__ __launch_bounds__(256) void resize_kernel(
    const float* __restrict__ cv, float* __restrict__ out, float* __restrict__ pmax)
{
    const int t = threadIdx.x;
    const int idx = blockIdx.x * 256 + t;
    const int j = idx % WC;
    const int rest = idx / WC;
    const int i = rest % HC;
    const int br = rest / HC;

    float fy = (i + 32.5f) * (1.0f/384.0f);
    float fx = (j + 32.5f) * (1.0f/224.0f);

    const float* p = cv + ((size_t)br*OY + i)*OX + j;
    float v00 = p[0], v01 = p[1], v10 = p[OX], v11 = p[OX+1];
    float v = (1.f-fy)*((1.f-fx)*v00 + fx*v01) + fy*((1.f-fx)*v10 + fx*v11);
    out[idx] = v;

    __shared__ float sm[4];
    float m = wave_max(v);
    if ((t & 63) == 0) sm[t >> 6] = m;
    __syncthreads();
    if (t == 0) pmax[blockIdx.x] = fmaxf(fmaxf(sm[0], sm[1]), fmaxf(sm[2], sm[3]));
}

__global__ __launch_bounds__(256) void reduce_kernel(
    const float* __restrict__ part, float* __restrict__ res, int n, int is_sum)
{
    const int b = blockIdx.x;
    const int t = threadIdx.x;
    const float* p = part + (size_t)b*n;
    float v = is_sum ? 0.f : -3.0e38f;
    for (int k = t; k < n; k += 256) v = is_sum ? (v + p[k]) : fmaxf(v, p[k]);
    __shared__ float sm[4];
    float w = is_sum ? wave_sum(v) : wave_max(v);
    if ((t & 63) == 0) sm[t >> 6] = w;
    __syncthreads();
    if (t == 0) {
        res[b] = is_sum ? (sm[0]+sm[1]+sm[2]+sm[3])
                        : fmaxf(fmaxf(sm[0], sm[1]), fmaxf(sm[2], sm[3]));
    }
}

__global__ __launch_bounds__(256) void exp_kernel(
    float* __restrict__ out, const float* __restrict__ bmax, float* __restrict__ psum)
{
    const int t = threadIdx.x;
    const int idx = blockIdx.x * 256 + t;
    const int b = blockIdx.x / BLKS_PER_BATCH;
    float e = expf(out[idx] - bmax[b]);
    out[idx] = e;
    __shared__ float sm[4];
    float s = wave_sum(e);
    if ((t & 63) == 0) sm[t >> 6] = s;
    __syncthreads();
    if (t == 0) psum[blockIdx.x] = sm[0]+sm[1]+sm[2]+sm[3];
}

__global__ __launch_bounds__(256) void scale_kernel(
    float* __restrict__ out, const float* __restrict__ bsum)
{
    const int idx = blockIdx.x * 256 + threadIdx.x;
    const int b = blockIdx.x / BLKS_PER_BATCH;
    out[idx] = out[idx] / bsum[b];
}

extern "C" void kernel_launch(void* const* d_in, const int* in_sizes, int n_in,
                              void* d_out, int out_size, void* d_ws, size_t ws_size,
                              hipStream_t stream)
{
    const float* logits = (const float*)d_in[0];   // (4,3,384,224) fp32
    const float* wk     = (const float*)d_in[1];   // (144,3,64,64) fp32
    float* out = (float*)d_out;                    // (4,36,320,160) fp32
    char*  wsB = (char*)d_ws;

    // workspace layout (bytes)
    float* convOut = (float*)wsB;                              // 7,442,064 f32 = 29,768,256 B
    u16*   wth     = (u16*)(wsB + 29768256);                   // 2,359,296 u16 = 4,718,592 B
    u16*   wtl     = (u16*)(wsB + 29768256 + 4718592);         // 4,718,592 B
    float* pmax    = (float*)(wsB + 29768256 + 2*4718592);     // 28800 f32
    float* psum    = pmax + 28800;
    float* bmax    = psum + 28800;
    float* bsum    = bmax + 8;

    hipLaunchKernelGGL(prep_weights, dim3(9216),  dim3(256), 0, stream, wk, wth, wtl);
    hipLaunchKernelGGL(conv_mfma,    dim3(2, OY, B_), dim3(256), 0, stream, logits, wth, wtl, convOut);
    hipLaunchKernelGGL(resize_kernel, dim3(28800), dim3(256), 0, stream, convOut, out, pmax);
    hipLaunchKernelGGL(reduce_kernel, dim3(4),     dim3(256), 0, stream, pmax, bmax, BLKS_PER_BATCH, 0);
    hipLaunchKernelGGL(exp_kernel,    dim3(28800), dim3(256), 0, stream, out, bmax, psum);
    hipLaunchKernelGGL(reduce_kernel, dim3(4),     dim3(256), 0, stream, psum, bsum, BLKS_PER_BATCH, 1);
    hipLaunchKernelGGL(scale_kernel,  dim3(28800), dim3(256), 0, stream, out, bsum);
}